// Round 2
// baseline (747.333 us; speedup 1.0000x reference)
//
#include <hip/hip_runtime.h>

typedef unsigned short u16;
typedef short bf16x8 __attribute__((ext_vector_type(8)));
typedef float f32x4 __attribute__((ext_vector_type(4)));
typedef u16 u16x4 __attribute__((ext_vector_type(4)));

#define SCALE_Q 0.044194173824159216f   // 1/sqrt(512)

__device__ __forceinline__ u16 f2b(float f){   // fp32 -> bf16 RNE
  unsigned u = __float_as_uint(f);
  u += 0x7fffu + ((u >> 16) & 1u);
  return (u16)(u >> 16);
}

__device__ __forceinline__ void gload16(const void* g, void* l){
  __builtin_amdgcn_global_load_lds(
      (const __attribute__((address_space(1))) void*)g,
      (__attribute__((address_space(3))) void*)l, 16, 0, 0);
}

__device__ __forceinline__ float qmax16(float v){
  v = fmaxf(v, __shfl_xor(v, 1)); v = fmaxf(v, __shfl_xor(v, 2));
  v = fmaxf(v, __shfl_xor(v, 4)); v = fmaxf(v, __shfl_xor(v, 8));
  return v;
}
__device__ __forceinline__ float qsum16(float v){
  v += __shfl_xor(v, 1); v += __shfl_xor(v, 2);
  v += __shfl_xor(v, 4); v += __shfl_xor(v, 8);
  return v;
}

// ---------------- GroupNorm stats: one block per (b, group) ----------------
__global__ __launch_bounds__(256) void gn_stats(const float* __restrict__ x,
                                                float* __restrict__ stats){
  int bg = blockIdx.x;                       // 0..127
  const float4* p4 = (const float4*)(x + (size_t)bg * 65536);
  float s = 0.f, ss = 0.f;
  for (int i = threadIdx.x; i < 16384; i += 256){
    float4 v = p4[i];
    s  += v.x + v.y + v.z + v.w;
    ss += v.x*v.x + v.y*v.y + v.z*v.z + v.w*v.w;
  }
  for (int off = 32; off; off >>= 1){
    s  += __shfl_down(s, off);
    ss += __shfl_down(ss, off);
  }
  __shared__ float as_[4], bs_[4];
  int wid = threadIdx.x >> 6, lid = threadIdx.x & 63;
  if (lid == 0){ as_[wid] = s; bs_[wid] = ss; }
  __syncthreads();
  if (threadIdx.x == 0){
    float S = as_[0]+as_[1]+as_[2]+as_[3], SS = bs_[0]+bs_[1]+bs_[2]+bs_[3];
    float mean = S * (1.f/65536.f);
    float var  = SS * (1.f/65536.f) - mean*mean;
    stats[2*bg]   = mean;
    stats[2*bg+1] = rsqrtf(var + 1e-6f);
  }
}

// ------- normalize + affine + transpose [b,c,N] -> t[b,N,c] (bf16) ---------
__global__ __launch_bounds__(256) void gn_apply_T(const float* __restrict__ x,
                                                  const float* __restrict__ stats,
                                                  const float* __restrict__ gamma,
                                                  const float* __restrict__ beta,
                                                  u16* __restrict__ t){
  __shared__ float tile[32][33];
  int nb = blockIdx.x, cb = blockIdx.y, b = blockIdx.z;
  int tx = threadIdx.x & 31, ty = threadIdx.x >> 5;
  int n0 = nb * 32, c0 = cb * 32;
  #pragma unroll
  for (int i = 0; i < 4; i++){
    int ch = c0 + ty + i*8;
    float mean = stats[2*((b<<5) + (ch>>4))];
    float rstd = stats[2*((b<<5) + (ch>>4)) + 1];
    float v = x[(((size_t)b*512 + ch) << 12) + n0 + tx];
    tile[ty + i*8][tx] = (v - mean) * rstd * gamma[ch] + beta[ch];
  }
  __syncthreads();
  #pragma unroll
  for (int i = 0; i < 4; i++){
    int n = n0 + ty + i*8;
    int ch = c0 + tx;
    t[((size_t)((b<<12) + n))*512 + ch] = f2b(tile[tx][ty + i*8]);
  }
}

// ---------------- fp32 -> bf16 weight conversion (4 matrices) --------------
__global__ __launch_bounds__(256) void w2bf(const float* __restrict__ a,
                                            const float* __restrict__ b,
                                            const float* __restrict__ c,
                                            const float* __restrict__ d,
                                            u16* __restrict__ o){
  int idx = blockIdx.x * 256 + threadIdx.x;         // 0..262143 float4 units
  int which = idx >> 16;
  const float4* src = (const float4*)(which == 0 ? a : which == 1 ? b : which == 2 ? c : d);
  float4 v = src[idx & 65535];
  u16x4 pk;
  pk.x = f2b(v.x); pk.y = f2b(v.y); pk.z = f2b(v.z); pk.w = f2b(v.w);
  *(u16x4*)(o + (size_t)idx*4) = pk;
}

// ------------- fused QKV gemm: grid (128, 12); y>>2 selects matrix ---------
// A bf16 [16384,512] row-major, Wcat bf16 [1536,512] (Wq;Wk;Wv rows, B^T form)
// mat 0 -> Q [b,N,c]*SCALE_Q ; mat 1 -> K [b,N,c] ; mat 2 -> V^T [b,c,N]
__global__ __launch_bounds__(256, 2) void qkv_gemm(const u16* __restrict__ A,
                                                   const u16* __restrict__ Wcat,
                                                   const float* __restrict__ qbias,
                                                   const float* __restrict__ kbias,
                                                   const float* __restrict__ vbias,
                                                   u16* __restrict__ qo,
                                                   u16* __restrict__ ko,
                                                   u16* __restrict__ vo){
  __shared__ __align__(16) u16 As[128*32];
  __shared__ __align__(16) u16 Bs[128*32];
  const int t = threadIdx.x;
  const int w = t >> 6, ln = t & 63;
  const int wr = w >> 1, wc = w & 1;
  const int q4 = ln >> 4, l15 = ln & 15;
  const int y = blockIdx.y;
  const int mat = y >> 2, yb = y & 3;
  const u16* Ab = A    + (size_t)blockIdx.x * 128 * 512;
  const u16* Bb = Wcat + (size_t)y * 128 * 512;
  f32x4 acc[4][4];
  #pragma unroll
  for (int i = 0; i < 4; i++)
    #pragma unroll
    for (int j = 0; j < 4; j++){
      acc[i][j][0]=0.f; acc[i][j][1]=0.f; acc[i][j][2]=0.f; acc[i][j][3]=0.f;
    }
  for (int kt = 0; kt < 16; ++kt){
    #pragma unroll
    for (int i = 0; i < 2; i++){
      int idx = i*256 + t;                       // 0..511
      gload16(Ab + (size_t)(idx>>2)*512 + kt*32 + (idx&3)*8, As + (size_t)idx*8);
      gload16(Bb + (size_t)(idx>>2)*512 + kt*32 + (idx&3)*8, Bs + (size_t)idx*8);
    }
    __syncthreads();
    bf16x8 af[4], bf[4];
    #pragma unroll
    for (int mt = 0; mt < 4; mt++)
      af[mt] = *(const bf16x8*)(As + (wr*64 + mt*16 + l15)*32 + q4*8);
    #pragma unroll
    for (int nt = 0; nt < 4; nt++)
      bf[nt] = *(const bf16x8*)(Bs + (wc*64 + nt*16 + l15)*32 + q4*8);
    #pragma unroll
    for (int mt = 0; mt < 4; mt++)
      #pragma unroll
      for (int nt = 0; nt < 4; nt++)
        acc[mt][nt] = __builtin_amdgcn_mfma_f32_16x16x32_bf16(af[mt], bf[nt], acc[mt][nt], 0, 0, 0);
    __syncthreads();
  }
  const int row0 = blockIdx.x*128 + wr*64;
  const int col0 = yb*128 + wc*64;               // column within this matrix
  const float* bias = (mat == 0) ? qbias : (mat == 1) ? kbias : vbias;
  if (mat < 2){
    u16* out = (mat == 0) ? qo : ko;
    float sc = (mat == 0) ? SCALE_Q : 1.f;
    #pragma unroll
    for (int nt = 0; nt < 4; nt++){
      int n = col0 + nt*16 + l15;
      float bv = bias[n];
      #pragma unroll
      for (int mt = 0; mt < 4; mt++){
        int m0 = row0 + mt*16 + q4*4;
        #pragma unroll
        for (int r = 0; r < 4; r++)
          out[(size_t)(m0 + r)*512 + n] = f2b((acc[mt][nt][r] + bv) * sc);
      }
    }
  } else {
    #pragma unroll
    for (int nt = 0; nt < 4; nt++){
      int n = col0 + nt*16 + l15;
      float bv = bias[n];
      #pragma unroll
      for (int mt = 0; mt < 4; mt++){
        int m0 = row0 + mt*16 + q4*4;
        int bb = m0 >> 12, tok = m0 & 4095;
        u16x4 pk;
        pk.x = f2b(acc[mt][nt][0] + bv);
        pk.y = f2b(acc[mt][nt][1] + bv);
        pk.z = f2b(acc[mt][nt][2] + bv);
        pk.w = f2b(acc[mt][nt][3] + bv);
        *(u16x4*)(vo + (((size_t)(bb*512 + n)) << 12) + tok) = pk;
      }
    }
  }
}

// ----------- out-proj gemm + bias + residual + transpose (fp32 out) --------
__global__ __launch_bounds__(256, 2) void out_gemm(const u16* __restrict__ A,
                                                   const u16* __restrict__ Bw,
                                                   const float* __restrict__ bias,
                                                   float* __restrict__ out,
                                                   const float* __restrict__ resid){
  __shared__ __align__(16) u16 As[128*32];
  __shared__ __align__(16) u16 Bs[128*32];
  const int t = threadIdx.x;
  const int w = t >> 6, ln = t & 63;
  const int wr = w >> 1, wc = w & 1;
  const int q4 = ln >> 4, l15 = ln & 15;
  const u16* Ab = A  + (size_t)blockIdx.x * 128 * 512;
  const u16* Bb = Bw + (size_t)blockIdx.y * 128 * 512;
  f32x4 acc[4][4];
  #pragma unroll
  for (int i = 0; i < 4; i++)
    #pragma unroll
    for (int j = 0; j < 4; j++){
      acc[i][j][0]=0.f; acc[i][j][1]=0.f; acc[i][j][2]=0.f; acc[i][j][3]=0.f;
    }
  for (int kt = 0; kt < 16; ++kt){
    #pragma unroll
    for (int i = 0; i < 2; i++){
      int idx = i*256 + t;
      gload16(Ab + (size_t)(idx>>2)*512 + kt*32 + (idx&3)*8, As + (size_t)idx*8);
      gload16(Bb + (size_t)(idx>>2)*512 + kt*32 + (idx&3)*8, Bs + (size_t)idx*8);
    }
    __syncthreads();
    bf16x8 af[4], bf[4];
    #pragma unroll
    for (int mt = 0; mt < 4; mt++)
      af[mt] = *(const bf16x8*)(As + (wr*64 + mt*16 + l15)*32 + q4*8);
    #pragma unroll
    for (int nt = 0; nt < 4; nt++)
      bf[nt] = *(const bf16x8*)(Bs + (wc*64 + nt*16 + l15)*32 + q4*8);
    #pragma unroll
    for (int mt = 0; mt < 4; mt++)
      #pragma unroll
      for (int nt = 0; nt < 4; nt++)
        acc[mt][nt] = __builtin_amdgcn_mfma_f32_16x16x32_bf16(af[mt], bf[nt], acc[mt][nt], 0, 0, 0);
    __syncthreads();
  }
  const int row0 = blockIdx.x*128 + wr*64;
  const int col0 = blockIdx.y*128 + wc*64;
  #pragma unroll
  for (int nt = 0; nt < 4; nt++){
    int n = col0 + nt*16 + l15;
    float bv = bias[n];
    #pragma unroll
    for (int mt = 0; mt < 4; mt++){
      int m0 = row0 + mt*16 + q4*4;
      int bb = m0 >> 12, tok = m0 & 4095;
      size_t base = (((size_t)(bb*512 + n)) << 12) + tok;
      float4 xr = *(const float4*)(resid + base);
      float4 ov;
      ov.x = acc[mt][nt][0] + bv + xr.x;
      ov.y = acc[mt][nt][1] + bv + xr.y;
      ov.z = acc[mt][nt][2] + bv + xr.z;
      ov.w = acc[mt][nt][3] + bv + xr.w;
      *(float4*)(out + base) = ov;
    }
  }
}

// ---------------------------- flash attention ------------------------------
// q[b,N,512] pre-scaled, k[b,N,512], vT[b,512,N]; O bf16 [b,N,512]
// BM=64 q rows/block, BN=64 kv rows/iter, 512 threads (8 waves), 1 block/CU.
// Softmax in-register (shuffle) + 2-way LDS exchange between column halves.
// Pipelining: V prefetched to regs during PV(j-1); K DMA'd to LDS after B3 so
// every compiler barrier-drain finds the loads (nearly) complete.
__global__ __launch_bounds__(512, 2) void attn_fwd(const u16* __restrict__ q,
                                                   const u16* __restrict__ k,
                                                   const u16* __restrict__ vT,
                                                   u16* __restrict__ outO){
  __shared__ __align__(16) u16 Kt[16*64*32];     // [ks][kvrow 64][kc 32]  64KB
  __shared__ __align__(16) u16 Vt[2*512*32];     // [kb][c 512][kc 32]     64KB
  __shared__ __align__(16) u16 Pb[64*72];        // [qrow][kv] +8 pad     9216B
  __shared__ __align__(16) float pmL[2*64];      // [ch][row] partial max
  __shared__ __align__(16) float psL[2*64];      // [ch][row] partial sum
  __shared__ __align__(16) float aL[64];         // alpha per row
  __shared__ __align__(16) float lL[64];         // final l per row

  const int t = threadIdx.x, w = t >> 6, ln = t & 63;
  const int q4 = ln >> 4, l15 = ln & 15;
  const int rt = w >> 1, ch = w & 1;             // S role: row-tile, col-half
  const int b = blockIdx.y, q0 = blockIdx.x * 64;
  const u16* qg = q  + ((size_t)b << 21);
  const u16* kg = k  + ((size_t)b << 21);
  const u16* vg = vT + ((size_t)b << 21);

  // Q fragments: rows rt*16 + l15, all 512 channels (64 VGPRs)
  bf16x8 qf[16];
  {
    const u16* qr = qg + (size_t)(q0 + rt*16 + l15) * 512;
    #pragma unroll
    for (int ks = 0; ks < 16; ks++) qf[ks] = *(const bf16x8*)(qr + ks*32 + q4*8);
  }
  // O accumulator: PV role: wave owns cols [64w, 64w+64), all 64 rows (64 VGPRs)
  f32x4 oacc[4][4];
  #pragma unroll
  for (int i = 0; i < 4; i++)
    #pragma unroll
    for (int j = 0; j < 4; j++){
      oacc[i][j][0]=0.f; oacc[i][j][1]=0.f; oacc[i][j][2]=0.f; oacc[i][j][3]=0.f;
    }
  f32x4 mrow, lrow;
  mrow[0]=-1e30f; mrow[1]=-1e30f; mrow[2]=-1e30f; mrow[3]=-1e30f;
  lrow[0]=0.f; lrow[1]=0.f; lrow[2]=0.f; lrow[3]=0.f;

  float4 vpre[8];
  // prologue: stage tile 0
  {
    const int k0 = 0;
    #pragma unroll
    for (int i = 0; i < 8; i++){
      int ci = i*512 + t;                        // K: [ks][kr][4 chunks]
      int ks = ci >> 8, kr = (ci >> 2) & 63, h = ci & 3;
      gload16(kg + (size_t)(k0 + kr)*512 + ks*32 + h*8, Kt + (size_t)ci*8);
    }
    #pragma unroll
    for (int i = 0; i < 8; i++){
      int ci = i*512 + t;                        // V: [kb][c][4 chunks]
      int kb = ci >> 11, c = (ci >> 2) & 511, h = ci & 3;
      vpre[i] = *(const float4*)(vg + (size_t)c*4096 + k0 + kb*32 + h*8);
    }
  }

  for (int j = 0; j < 64; j++){
    __syncthreads();                             // B0: PV(j-1) done; K-DMA(j) drained
    #pragma unroll
    for (int i = 0; i < 8; i++)
      ((float4*)Vt)[i*512 + t] = vpre[i];        // write V tile j
    __syncthreads();                             // B1: Kt/Vt ready

    // ---- S = Q K^T : wave (rt, ch) computes rows rt*16, cols ch*32..+32 ----
    f32x4 s0, s1;
    s0[0]=0.f; s0[1]=0.f; s0[2]=0.f; s0[3]=0.f;
    s1[0]=0.f; s1[1]=0.f; s1[2]=0.f; s1[3]=0.f;
    #pragma unroll
    for (int ks = 0; ks < 16; ks++){
      bf16x8 kf0 = *(const bf16x8*)(Kt + ((ks*64 + ch*32 + l15) << 5) + q4*8);
      bf16x8 kf1 = *(const bf16x8*)(Kt + ((ks*64 + ch*32 + 16 + l15) << 5) + q4*8);
      s0 = __builtin_amdgcn_mfma_f32_16x16x32_bf16(qf[ks], kf0, s0, 0, 0, 0);
      s1 = __builtin_amdgcn_mfma_f32_16x16x32_bf16(qf[ks], kf1, s1, 0, 0, 0);
    }
    // ---- partial row max over this wave's 32 cols (in-register) ----
    f32x4 pm;
    #pragma unroll
    for (int r = 0; r < 4; r++) pm[r] = qmax16(fmaxf(s0[r], s1[r]));
    if (l15 == 0) *(f32x4*)(pmL + ch*64 + rt*16 + q4*4) = pm;
    __syncthreads();                             // B2: partial maxes ready
    f32x4 pmo = *(const f32x4*)(pmL + (ch^1)*64 + rt*16 + q4*4);
    f32x4 mnew, alpha, ps;
    #pragma unroll
    for (int r = 0; r < 4; r++){
      mnew[r]  = fmaxf(mrow[r], fmaxf(pm[r], pmo[r]));
      alpha[r] = __expf(mrow[r] - mnew[r]);
      mrow[r]  = mnew[r];
      float e0 = __expf(s0[r] - mnew[r]);
      float e1 = __expf(s1[r] - mnew[r]);
      s0[r] = e0; s1[r] = e1;                    // reuse regs as P values
      ps[r] = qsum16(e0 + e1);
      Pb[(rt*16 + q4*4 + r)*72 + ch*32 + l15]      = f2b(e0);
      Pb[(rt*16 + q4*4 + r)*72 + ch*32 + 16 + l15] = f2b(e1);
    }
    if (l15 == 0){
      *(f32x4*)(psL + ch*64 + rt*16 + q4*4) = ps;
      if (ch == 0) *(f32x4*)(aL + rt*16 + q4*4) = alpha;
    }
    __syncthreads();                             // B3: P, psum, alpha ready
    if (ch == 0){
      f32x4 pso = *(const f32x4*)(psL + 64 + rt*16 + q4*4);
      #pragma unroll
      for (int r = 0; r < 4; r++) lrow[r] = lrow[r]*alpha[r] + ps[r] + pso[r];
    }
    // ---- issue next tile's K DMA + V register loads (overlap with PV) ----
    {
      const int k0n = ((j + 1) & 63) * 64;
      #pragma unroll
      for (int i = 0; i < 8; i++){
        int ci = i*512 + t;
        int ks = ci >> 8, kr = (ci >> 2) & 63, h = ci & 3;
        gload16(kg + (size_t)(k0n + kr)*512 + ks*32 + h*8, Kt + (size_t)ci*8);
      }
      #pragma unroll
      for (int i = 0; i < 8; i++){
        int ci = i*512 + t;
        int kb = ci >> 11, c = (ci >> 2) & 511, h = ci & 3;
        vpre[i] = *(const float4*)(vg + (size_t)c*4096 + k0n + kb*32 + h*8);
      }
    }
    // ---- O = O*alpha + P V : wave owns col strip [64w, 64w+64) ----
    {
      bf16x8 vf0[4], vf1[4];
      #pragma unroll
      for (int ctl = 0; ctl < 4; ctl++){
        int c = w*64 + ctl*16 + l15;
        vf0[ctl] = *(const bf16x8*)(Vt + ((size_t)c << 5) + q4*8);
        vf1[ctl] = *(const bf16x8*)(Vt + (((size_t)(512 + c)) << 5) + q4*8);
      }
      f32x4 al[4];
      #pragma unroll
      for (int rr = 0; rr < 4; rr++) al[rr] = *(const f32x4*)(aL + rr*16 + q4*4);
      #pragma unroll
      for (int rr = 0; rr < 4; rr++){
        bf16x8 pf0 = *(const bf16x8*)(Pb + (rr*16 + l15)*72 + q4*8);
        bf16x8 pf1 = *(const bf16x8*)(Pb + (rr*16 + l15)*72 + 32 + q4*8);
        #pragma unroll
        for (int ctl = 0; ctl < 4; ctl++){
          f32x4 a = oacc[rr][ctl];
          a[0] *= al[rr][0]; a[1] *= al[rr][1]; a[2] *= al[rr][2]; a[3] *= al[rr][3];
          a = __builtin_amdgcn_mfma_f32_16x16x32_bf16(pf0, vf0[ctl], a, 0, 0, 0);
          a = __builtin_amdgcn_mfma_f32_16x16x32_bf16(pf1, vf1[ctl], a, 0, 0, 0);
          oacc[rr][ctl] = a;
        }
      }
    }
  }
  // ---- epilogue: O /= l, write bf16 [b][tok][c] ----
  if (ch == 0 && l15 == 0) *(f32x4*)(lL + rt*16 + q4*4) = lrow;
  __syncthreads();
  #pragma unroll
  for (int rr = 0; rr < 4; rr++){
    f32x4 lv = *(const f32x4*)(lL + rr*16 + q4*4);
    float i0 = 1.f/lv[0], i1 = 1.f/lv[1], i2 = 1.f/lv[2], i3 = 1.f/lv[3];
    #pragma unroll
    for (int ctl = 0; ctl < 4; ctl++){
      int col = w*64 + ctl*16 + l15;
      u16* op = outO + ((size_t)((b<<12) + q0 + rr*16 + q4*4))*512 + col;
      op[0]    = f2b(oacc[rr][ctl][0]*i0);
      op[512]  = f2b(oacc[rr][ctl][1]*i1);
      op[1024] = f2b(oacc[rr][ctl][2]*i2);
      op[1536] = f2b(oacc[rr][ctl][3]*i3);
    }
  }
}

extern "C" void kernel_launch(void* const* d_in, const int* in_sizes, int n_in,
                              void* d_out, int out_size, void* d_ws, size_t ws_size,
                              hipStream_t stream){
  const float* x     = (const float*)d_in[0];
  const float* gamma = (const float*)d_in[1];
  const float* beta  = (const float*)d_in[2];
  const float* wq_w  = (const float*)d_in[3];
  const float* wq_b  = (const float*)d_in[4];
  const float* wk_w  = (const float*)d_in[5];
  const float* wk_b  = (const float*)d_in[6];
  const float* wv_w  = (const float*)d_in[7];
  const float* wv_b  = (const float*)d_in[8];
  const float* out_w = (const float*)d_in[9];
  const float* out_b = (const float*)d_in[10];

  char* ws = (char*)d_ws;
  float* stats = (float*)ws;                                   // 1 KB
  u16* tbuf = (u16*)(ws + 4096);                               // 16 MB (t, then O)
  size_t off = 4096 + (size_t)16*1024*1024;
  u16* Wcat = (u16*)(ws + off); off += (size_t)4*512*512*2;    // 2 MB (Wq,Wk,Wv,Wo)
  u16* qb   = (u16*)(ws + off); off += (size_t)16*1024*1024;
  u16* kb   = (u16*)(ws + off); off += (size_t)16*1024*1024;
  u16* vTb  = (u16*)(ws + off); off += (size_t)16*1024*1024;   // ~67 MB total

  gn_stats<<<128, 256, 0, stream>>>(x, stats);
  gn_apply_T<<<dim3(128, 16, 4), 256, 0, stream>>>(x, stats, gamma, beta, tbuf);
  w2bf<<<1024, 256, 0, stream>>>(wq_w, wk_w, wv_w, out_w, Wcat);
  u16* Wo = Wcat + 3*512*512;
  qkv_gemm<<<dim3(128, 12), 256, 0, stream>>>(tbuf, Wcat, wq_b, wk_b, wv_b,
                                              qb, kb, vTb);
  attn_fwd<<<dim3(64, 4), 512, 0, stream>>>(qb, kb, vTb, tbuf);   // O overwrites t
  out_gemm<<<dim3(128, 4), 256, 0, stream>>>(tbuf, Wo, out_b, (float*)d_out, x);
}

// Round 3
// 554.315 us; speedup vs baseline: 1.3482x; 1.3482x over previous
//
#include <hip/hip_runtime.h>

typedef unsigned short u16;
typedef short bf16x8 __attribute__((ext_vector_type(8)));
typedef float f32x4 __attribute__((ext_vector_type(4)));
typedef u16 u16x4 __attribute__((ext_vector_type(4)));

#define SCALE_Q 0.044194173824159216f   // 1/sqrt(512)

__device__ __forceinline__ u16 f2b(float f){   // fp32 -> bf16 RNE
  unsigned u = __float_as_uint(f);
  u += 0x7fffu + ((u >> 16) & 1u);
  return (u16)(u >> 16);
}

__device__ __forceinline__ void gload16(const void* g, void* l){
  __builtin_amdgcn_global_load_lds(
      (const __attribute__((address_space(1))) void*)g,
      (__attribute__((address_space(3))) void*)l, 16, 0, 0);
}

__device__ __forceinline__ float qmax16(float v){
  v = fmaxf(v, __shfl_xor(v, 1)); v = fmaxf(v, __shfl_xor(v, 2));
  v = fmaxf(v, __shfl_xor(v, 4)); v = fmaxf(v, __shfl_xor(v, 8));
  return v;
}
__device__ __forceinline__ float qsum16(float v){
  v += __shfl_xor(v, 1); v += __shfl_xor(v, 2);
  v += __shfl_xor(v, 4); v += __shfl_xor(v, 8);
  return v;
}

// ---------------- GroupNorm stats: one block per (b, group) ----------------
__global__ __launch_bounds__(256) void gn_stats(const float* __restrict__ x,
                                                float* __restrict__ stats){
  int bg = blockIdx.x;                       // 0..127
  const float4* p4 = (const float4*)(x + (size_t)bg * 65536);
  float s = 0.f, ss = 0.f;
  for (int i = threadIdx.x; i < 16384; i += 256){
    float4 v = p4[i];
    s  += v.x + v.y + v.z + v.w;
    ss += v.x*v.x + v.y*v.y + v.z*v.z + v.w*v.w;
  }
  for (int off = 32; off; off >>= 1){
    s  += __shfl_down(s, off);
    ss += __shfl_down(ss, off);
  }
  __shared__ float as_[4], bs_[4];
  int wid = threadIdx.x >> 6, lid = threadIdx.x & 63;
  if (lid == 0){ as_[wid] = s; bs_[wid] = ss; }
  __syncthreads();
  if (threadIdx.x == 0){
    float S = as_[0]+as_[1]+as_[2]+as_[3], SS = bs_[0]+bs_[1]+bs_[2]+bs_[3];
    float mean = S * (1.f/65536.f);
    float var  = SS * (1.f/65536.f) - mean*mean;
    stats[2*bg]   = mean;
    stats[2*bg+1] = rsqrtf(var + 1e-6f);
  }
}

// ------- normalize + affine + transpose [b,c,N] -> t[b,N,c] (bf16) ---------
__global__ __launch_bounds__(256) void gn_apply_T(const float* __restrict__ x,
                                                  const float* __restrict__ stats,
                                                  const float* __restrict__ gamma,
                                                  const float* __restrict__ beta,
                                                  u16* __restrict__ t){
  __shared__ float tile[32][33];
  int nb = blockIdx.x, cb = blockIdx.y, b = blockIdx.z;
  int tx = threadIdx.x & 31, ty = threadIdx.x >> 5;
  int n0 = nb * 32, c0 = cb * 32;
  #pragma unroll
  for (int i = 0; i < 4; i++){
    int ch = c0 + ty + i*8;
    float mean = stats[2*((b<<5) + (ch>>4))];
    float rstd = stats[2*((b<<5) + (ch>>4)) + 1];
    float v = x[(((size_t)b*512 + ch) << 12) + n0 + tx];
    tile[ty + i*8][tx] = (v - mean) * rstd * gamma[ch] + beta[ch];
  }
  __syncthreads();
  #pragma unroll
  for (int i = 0; i < 4; i++){
    int n = n0 + ty + i*8;
    int ch = c0 + tx;
    t[((size_t)((b<<12) + n))*512 + ch] = f2b(tile[tx][ty + i*8]);
  }
}

// ---------------- fp32 -> bf16 weight conversion (4 matrices) --------------
__global__ __launch_bounds__(256) void w2bf(const float* __restrict__ a,
                                            const float* __restrict__ b,
                                            const float* __restrict__ c,
                                            const float* __restrict__ d,
                                            u16* __restrict__ o){
  int idx = blockIdx.x * 256 + threadIdx.x;         // 0..262143 float4 units
  int which = idx >> 16;
  const float4* src = (const float4*)(which == 0 ? a : which == 1 ? b : which == 2 ? c : d);
  float4 v = src[idx & 65535];
  u16x4 pk;
  pk.x = f2b(v.x); pk.y = f2b(v.y); pk.z = f2b(v.z); pk.w = f2b(v.w);
  *(u16x4*)(o + (size_t)idx*4) = pk;
}

// ------------- fused QKV gemm: grid (128, 12); y>>2 selects matrix ---------
__global__ __launch_bounds__(256, 2) void qkv_gemm(const u16* __restrict__ A,
                                                   const u16* __restrict__ Wcat,
                                                   const float* __restrict__ qbias,
                                                   const float* __restrict__ kbias,
                                                   const float* __restrict__ vbias,
                                                   u16* __restrict__ qo,
                                                   u16* __restrict__ ko,
                                                   u16* __restrict__ vo){
  __shared__ __align__(16) u16 As[128*32];
  __shared__ __align__(16) u16 Bs[128*32];
  const int t = threadIdx.x;
  const int w = t >> 6, ln = t & 63;
  const int wr = w >> 1, wc = w & 1;
  const int q4 = ln >> 4, l15 = ln & 15;
  const int y = blockIdx.y;
  const int mat = y >> 2, yb = y & 3;
  const u16* Ab = A    + (size_t)blockIdx.x * 128 * 512;
  const u16* Bb = Wcat + (size_t)y * 128 * 512;
  f32x4 acc[4][4];
  #pragma unroll
  for (int i = 0; i < 4; i++)
    #pragma unroll
    for (int j = 0; j < 4; j++){
      acc[i][j][0]=0.f; acc[i][j][1]=0.f; acc[i][j][2]=0.f; acc[i][j][3]=0.f;
    }
  for (int kt = 0; kt < 16; ++kt){
    #pragma unroll
    for (int i = 0; i < 2; i++){
      int idx = i*256 + t;                       // 0..511
      gload16(Ab + (size_t)(idx>>2)*512 + kt*32 + (idx&3)*8, As + (size_t)idx*8);
      gload16(Bb + (size_t)(idx>>2)*512 + kt*32 + (idx&3)*8, Bs + (size_t)idx*8);
    }
    __syncthreads();
    bf16x8 af[4], bf[4];
    #pragma unroll
    for (int mt = 0; mt < 4; mt++)
      af[mt] = *(const bf16x8*)(As + (wr*64 + mt*16 + l15)*32 + q4*8);
    #pragma unroll
    for (int nt = 0; nt < 4; nt++)
      bf[nt] = *(const bf16x8*)(Bs + (wc*64 + nt*16 + l15)*32 + q4*8);
    #pragma unroll
    for (int mt = 0; mt < 4; mt++)
      #pragma unroll
      for (int nt = 0; nt < 4; nt++)
        acc[mt][nt] = __builtin_amdgcn_mfma_f32_16x16x32_bf16(af[mt], bf[nt], acc[mt][nt], 0, 0, 0);
    __syncthreads();
  }
  const int row0 = blockIdx.x*128 + wr*64;
  const int col0 = yb*128 + wc*64;               // column within this matrix
  const float* bias = (mat == 0) ? qbias : (mat == 1) ? kbias : vbias;
  if (mat < 2){
    u16* out = (mat == 0) ? qo : ko;
    float sc = (mat == 0) ? SCALE_Q : 1.f;
    #pragma unroll
    for (int nt = 0; nt < 4; nt++){
      int n = col0 + nt*16 + l15;
      float bv = bias[n];
      #pragma unroll
      for (int mt = 0; mt < 4; mt++){
        int m0 = row0 + mt*16 + q4*4;
        #pragma unroll
        for (int r = 0; r < 4; r++)
          out[(size_t)(m0 + r)*512 + n] = f2b((acc[mt][nt][r] + bv) * sc);
      }
    }
  } else {
    #pragma unroll
    for (int nt = 0; nt < 4; nt++){
      int n = col0 + nt*16 + l15;
      float bv = bias[n];
      #pragma unroll
      for (int mt = 0; mt < 4; mt++){
        int m0 = row0 + mt*16 + q4*4;
        int bb = m0 >> 12, tok = m0 & 4095;
        u16x4 pk;
        pk.x = f2b(acc[mt][nt][0] + bv);
        pk.y = f2b(acc[mt][nt][1] + bv);
        pk.z = f2b(acc[mt][nt][2] + bv);
        pk.w = f2b(acc[mt][nt][3] + bv);
        *(u16x4*)(vo + (((size_t)(bb*512 + n)) << 12) + tok) = pk;
      }
    }
  }
}

// ----------- out-proj gemm + bias + residual + transpose (fp32 out) --------
__global__ __launch_bounds__(256, 2) void out_gemm(const u16* __restrict__ A,
                                                   const u16* __restrict__ Bw,
                                                   const float* __restrict__ bias,
                                                   float* __restrict__ out,
                                                   const float* __restrict__ resid){
  __shared__ __align__(16) u16 As[128*32];
  __shared__ __align__(16) u16 Bs[128*32];
  const int t = threadIdx.x;
  const int w = t >> 6, ln = t & 63;
  const int wr = w >> 1, wc = w & 1;
  const int q4 = ln >> 4, l15 = ln & 15;
  const u16* Ab = A  + (size_t)blockIdx.x * 128 * 512;
  const u16* Bb = Bw + (size_t)blockIdx.y * 128 * 512;
  f32x4 acc[4][4];
  #pragma unroll
  for (int i = 0; i < 4; i++)
    #pragma unroll
    for (int j = 0; j < 4; j++){
      acc[i][j][0]=0.f; acc[i][j][1]=0.f; acc[i][j][2]=0.f; acc[i][j][3]=0.f;
    }
  for (int kt = 0; kt < 16; ++kt){
    #pragma unroll
    for (int i = 0; i < 2; i++){
      int idx = i*256 + t;
      gload16(Ab + (size_t)(idx>>2)*512 + kt*32 + (idx&3)*8, As + (size_t)idx*8);
      gload16(Bb + (size_t)(idx>>2)*512 + kt*32 + (idx&3)*8, Bs + (size_t)idx*8);
    }
    __syncthreads();
    bf16x8 af[4], bf[4];
    #pragma unroll
    for (int mt = 0; mt < 4; mt++)
      af[mt] = *(const bf16x8*)(As + (wr*64 + mt*16 + l15)*32 + q4*8);
    #pragma unroll
    for (int nt = 0; nt < 4; nt++)
      bf[nt] = *(const bf16x8*)(Bs + (wc*64 + nt*16 + l15)*32 + q4*8);
    #pragma unroll
    for (int mt = 0; mt < 4; mt++)
      #pragma unroll
      for (int nt = 0; nt < 4; nt++)
        acc[mt][nt] = __builtin_amdgcn_mfma_f32_16x16x32_bf16(af[mt], bf[nt], acc[mt][nt], 0, 0, 0);
    __syncthreads();
  }
  const int row0 = blockIdx.x*128 + wr*64;
  const int col0 = blockIdx.y*128 + wc*64;
  #pragma unroll
  for (int nt = 0; nt < 4; nt++){
    int n = col0 + nt*16 + l15;
    float bv = bias[n];
    #pragma unroll
    for (int mt = 0; mt < 4; mt++){
      int m0 = row0 + mt*16 + q4*4;
      int bb = m0 >> 12, tok = m0 & 4095;
      size_t base = (((size_t)(bb*512 + n)) << 12) + tok;
      float4 xr = *(const float4*)(resid + base);
      float4 ov;
      ov.x = acc[mt][nt][0] + bv + xr.x;
      ov.y = acc[mt][nt][1] + bv + xr.y;
      ov.z = acc[mt][nt][2] + bv + xr.z;
      ov.w = acc[mt][nt][3] + bv + xr.w;
      *(float4*)(out + base) = ov;
    }
  }
}

// ---------------------------- flash attention ------------------------------
// q[b,N,512] pre-scaled, k[b,N,512], vT[b,512,N]; O bf16 [b,N,512]
// BM=64, BN=32, 512 threads (8 waves), 1 block/CU (launch_bounds(512,1) ->
// 256-VGPR cap; R2's (512,2) meant 2 blocks/CU -> 128 cap -> spills).
// Waves 0-3: S rows w*16..+16, FULL 32 cols -> in-wave softmax, no exchange
// barrier. All 8 waves: PV on 64-col strips. 2 barriers/iter. K+V double-
// buffered via global_load_lds; DMA for tile j+1 issued after the P-barrier,
// drained at next iter's top barrier (one PV phase of latency cover).
__global__ __launch_bounds__(512, 1) void attn_fwd(const u16* __restrict__ q,
                                                   const u16* __restrict__ k,
                                                   const u16* __restrict__ vT,
                                                   u16* __restrict__ outO){
  __shared__ __align__(16) u16 Kt[2*16*32*32];   // [buf][ks16][row32][ch32] 64KB
  __shared__ __align__(16) u16 Vt[2*512*32];     // [buf][c512][kv32]        64KB
  __shared__ __align__(16) u16 Pb[64*40];        // [qrow][kv] stride 40     5KB
  __shared__ __align__(16) float aL[64];
  __shared__ __align__(16) float lL[64];

  const int t = threadIdx.x, w = t >> 6, ln = t & 63;
  const int q4 = ln >> 4, l15 = ln & 15;
  const int b = blockIdx.y, q0 = blockIdx.x * 64;
  const u16* qg = q  + ((size_t)b << 21);
  const u16* kg = k  + ((size_t)b << 21);
  const u16* vg = vT + ((size_t)b << 21);

  // Q fragments (waves 0-3 only): rows q0 + w*16 + l15, all 512 ch (64 VGPRs)
  bf16x8 qf[16];
  if (w < 4){
    const u16* qr = qg + (size_t)(q0 + w*16 + l15) * 512;
    #pragma unroll
    for (int ks = 0; ks < 16; ks++) qf[ks] = *(const bf16x8*)(qr + ks*32 + q4*8);
  }
  // O accumulator: wave owns cols [64w, 64w+64), all 64 rows (64 AGPRs)
  f32x4 oacc[4][4];
  #pragma unroll
  for (int i = 0; i < 4; i++)
    #pragma unroll
    for (int j = 0; j < 4; j++){
      oacc[i][j][0]=0.f; oacc[i][j][1]=0.f; oacc[i][j][2]=0.f; oacc[i][j][3]=0.f;
    }
  f32x4 mrow, lrow;
  mrow[0]=-1e30f; mrow[1]=-1e30f; mrow[2]=-1e30f; mrow[3]=-1e30f;
  lrow[0]=0.f; lrow[1]=0.f; lrow[2]=0.f; lrow[3]=0.f;

  // prologue: DMA tile 0 into buffer 0
  #pragma unroll
  for (int i = 0; i < 4; i++){                   // K: 2048 16B chunks
    int ci = i*512 + t;
    int ks = ci >> 7, row = (ci >> 2) & 31, h = ci & 3;
    gload16(kg + (size_t)row*512 + ks*32 + h*8, Kt + (size_t)ci*8);
  }
  #pragma unroll
  for (int i = 0; i < 4; i++){                   // V: 2048 16B chunks
    int ci = i*512 + t;
    int c = ci >> 2, h = ci & 3;
    gload16(vg + (size_t)c*4096 + h*8, Vt + (size_t)ci*8);
  }

  for (int j = 0; j < 128; ++j){
    __syncthreads();                             // B0: DMA(j) drained, prev PV done
    const u16* Kp = Kt + (j & 1) * 16384;
    const u16* Vp = Vt + (j & 1) * 16384;

    // ---- S + online softmax: waves 0-3, rows w*16..+16, cols 0..32 ----
    if (w < 4){
      f32x4 s0, s1;
      s0[0]=0.f; s0[1]=0.f; s0[2]=0.f; s0[3]=0.f;
      s1[0]=0.f; s1[1]=0.f; s1[2]=0.f; s1[3]=0.f;
      #pragma unroll
      for (int ks = 0; ks < 16; ks++){
        bf16x8 kf0 = *(const bf16x8*)(Kp + ks*1024 + l15*32 + q4*8);
        bf16x8 kf1 = *(const bf16x8*)(Kp + ks*1024 + (16 + l15)*32 + q4*8);
        s0 = __builtin_amdgcn_mfma_f32_16x16x32_bf16(qf[ks], kf0, s0, 0, 0, 0);
        s1 = __builtin_amdgcn_mfma_f32_16x16x32_bf16(qf[ks], kf1, s1, 0, 0, 0);
      }
      f32x4 alpha;
      #pragma unroll
      for (int r = 0; r < 4; r++){
        float pmx  = qmax16(fmaxf(s0[r], s1[r]));
        float mnew = fmaxf(mrow[r], pmx);
        alpha[r]   = __expf(mrow[r] - mnew);
        mrow[r]    = mnew;
        float e0 = __expf(s0[r] - mnew);
        float e1 = __expf(s1[r] - mnew);
        lrow[r] = lrow[r]*alpha[r] + qsum16(e0 + e1);
        Pb[(w*16 + q4*4 + r)*40 + l15]      = f2b(e0);
        Pb[(w*16 + q4*4 + r)*40 + 16 + l15] = f2b(e1);
      }
      if (l15 == 0) *(f32x4*)(aL + w*16 + q4*4) = alpha;
    }
    __syncthreads();                             // B1: P + alpha ready

    // ---- issue DMA for tile j+1 into buffer (j+1)&1 ----
    {
      const int jn = (j + 1) & 127;
      const int k0n = jn * 32;
      u16* Kn = Kt + ((j + 1) & 1) * 16384;
      u16* Vn = Vt + ((j + 1) & 1) * 16384;
      #pragma unroll
      for (int i = 0; i < 4; i++){
        int ci = i*512 + t;
        int ks = ci >> 7, row = (ci >> 2) & 31, h = ci & 3;
        gload16(kg + (size_t)(k0n + row)*512 + ks*32 + h*8, Kn + (size_t)ci*8);
      }
      #pragma unroll
      for (int i = 0; i < 4; i++){
        int ci = i*512 + t;
        int c = ci >> 2, h = ci & 3;
        gload16(vg + (size_t)c*4096 + k0n + h*8, Vn + (size_t)ci*8);
      }
    }

    // ---- PV: O = O*alpha + P V ; wave owns col strip [64w, 64w+64) ----
    {
      bf16x8 vf[4], pf[4];
      #pragma unroll
      for (int ct = 0; ct < 4; ct++)
        vf[ct] = *(const bf16x8*)(Vp + (w*64 + ct*16 + l15)*32 + q4*8);
      #pragma unroll
      for (int rt = 0; rt < 4; rt++)
        pf[rt] = *(const bf16x8*)(Pb + (rt*16 + l15)*40 + q4*8);
      f32x4 al[4];
      #pragma unroll
      for (int rt = 0; rt < 4; rt++) al[rt] = *(const f32x4*)(aL + rt*16 + q4*4);
      #pragma unroll
      for (int rt = 0; rt < 4; rt++)
        #pragma unroll
        for (int ct = 0; ct < 4; ct++){
          f32x4 a = oacc[rt][ct];
          a[0] *= al[rt][0]; a[1] *= al[rt][1]; a[2] *= al[rt][2]; a[3] *= al[rt][3];
          oacc[rt][ct] = __builtin_amdgcn_mfma_f32_16x16x32_bf16(pf[rt], vf[ct], a, 0, 0, 0);
        }
    }
  }

  // ---- epilogue: O /= l, write bf16 [b][tok][c] ----
  if (w < 4 && l15 == 0) *(f32x4*)(lL + w*16 + q4*4) = lrow;
  __syncthreads();
  #pragma unroll
  for (int rt = 0; rt < 4; rt++){
    f32x4 lv = *(const f32x4*)(lL + rt*16 + q4*4);
    float iv[4]; iv[0]=1.f/lv[0]; iv[1]=1.f/lv[1]; iv[2]=1.f/lv[2]; iv[3]=1.f/lv[3];
    #pragma unroll
    for (int ct = 0; ct < 4; ct++){
      int col = w*64 + ct*16 + l15;
      u16* op = outO + ((size_t)((b<<12) + q0 + rt*16 + q4*4))*512 + col;
      op[0]    = f2b(oacc[rt][ct][0]*iv[0]);
      op[512]  = f2b(oacc[rt][ct][1]*iv[1]);
      op[1024] = f2b(oacc[rt][ct][2]*iv[2]);
      op[1536] = f2b(oacc[rt][ct][3]*iv[3]);
    }
  }
}

extern "C" void kernel_launch(void* const* d_in, const int* in_sizes, int n_in,
                              void* d_out, int out_size, void* d_ws, size_t ws_size,
                              hipStream_t stream){
  const float* x     = (const float*)d_in[0];
  const float* gamma = (const float*)d_in[1];
  const float* beta  = (const float*)d_in[2];
  const float* wq_w  = (const float*)d_in[3];
  const float* wq_b  = (const float*)d_in[4];
  const float* wk_w  = (const float*)d_in[5];
  const float* wk_b  = (const float*)d_in[6];
  const float* wv_w  = (const float*)d_in[7];
  const float* wv_b  = (const float*)d_in[8];
  const float* out_w = (const float*)d_in[9];
  const float* out_b = (const float*)d_in[10];

  char* ws = (char*)d_ws;
  float* stats = (float*)ws;                                   // 1 KB
  u16* tbuf = (u16*)(ws + 4096);                               // 16 MB (t, then O)
  size_t off = 4096 + (size_t)16*1024*1024;
  u16* Wcat = (u16*)(ws + off); off += (size_t)4*512*512*2;    // 2 MB (Wq,Wk,Wv,Wo)
  u16* qb   = (u16*)(ws + off); off += (size_t)16*1024*1024;
  u16* kb   = (u16*)(ws + off); off += (size_t)16*1024*1024;
  u16* vTb  = (u16*)(ws + off); off += (size_t)16*1024*1024;   // ~67 MB total

  gn_stats<<<128, 256, 0, stream>>>(x, stats);
  gn_apply_T<<<dim3(128, 16, 4), 256, 0, stream>>>(x, stats, gamma, beta, tbuf);
  w2bf<<<1024, 256, 0, stream>>>(wq_w, wk_w, wv_w, out_w, Wcat);
  u16* Wo = Wcat + 3*512*512;
  qkv_gemm<<<dim3(128, 12), 256, 0, stream>>>(tbuf, Wcat, wq_b, wk_b, wv_b,
                                              qb, kb, vTb);
  attn_fwd<<<dim3(64, 4), 512, 0, stream>>>(qb, kb, vTb, tbuf);   // O overwrites t
  out_gemm<<<dim3(128, 4), 256, 0, stream>>>(tbuf, Wo, out_b, (float*)d_out, x);
}